// Round 1
// baseline (477.739 us; speedup 1.0000x reference)
//
#include <hip/hip_runtime.h>
#include <math.h>

#define KK 256
#define NN 65536
#define TT 64   // time-tile columns per block
#define WW 48   // scan lookback window; decay<=e^-1 -> tail error ~1e-20

// ---------------------------------------------------------------------------
// Kernel 1: Mu0[k] = mean(obs[k,:])/10 + 0.01 ; also zero loglik accumulator
// ---------------------------------------------------------------------------
__global__ __launch_bounds__(256) void mu0_kernel(const float* __restrict__ obs,
                                                  float* __restrict__ mu0,
                                                  float* __restrict__ out) {
  const int k = blockIdx.x;
  const int tid = threadIdx.x;
  const float* row = obs + (size_t)k * NN;
  float s = 0.f;
  for (int i = tid; i < NN; i += 256) s += row[i];
  __shared__ float red[256];
  red[tid] = s;
  __syncthreads();
  for (int off = 128; off > 0; off >>= 1) {
    if (tid < off) red[tid] += red[tid + off];
    __syncthreads();
  }
  if (tid == 0) {
    mu0[k] = red[0] * (1.0f / NN) * 0.1f + 0.01f;
    if (k == 0) out[0] = 0.f;  // zero loglik accumulator (d_out is poisoned)
  }
}

// ---------------------------------------------------------------------------
// Kernel 2: AT[k][j] = Alpha[j][k]  (transpose for coalesced GEMM reads)
// ---------------------------------------------------------------------------
__global__ __launch_bounds__(256) void prep_kernel(const float* __restrict__ Alpha,
                                                   float* __restrict__ AT) {
  const int k = blockIdx.x;
  const int j = threadIdx.x;
  AT[k * KK + j] = Alpha[j * KK + k];
}

// ---------------------------------------------------------------------------
// Kernel 3: lams0[j][t] = Mu0[j]  (coalesced broadcast fill)
// ---------------------------------------------------------------------------
__global__ __launch_bounds__(256) void lams0_kernel(const float* __restrict__ mu0,
                                                    float* __restrict__ out1) {
  size_t idx = (size_t)blockIdx.x * 1024 + threadIdx.x;
#pragma unroll
  for (int r = 0; r < 4; ++r) {
    out1[idx] = mu0[idx >> 16];  // row j = idx / 65536
    idx += 256;
  }
}

// ---------------------------------------------------------------------------
// Kernel 4: fused windowed-scan + GEMM + softplus + loglik partial
//   Block b handles time columns [t0, t0+TT).
//   Sval[k,u] = Beta[k]*G[k,u],  G[k,u] = decay_k*(G[k,u-1]+obs[k,u-1])
//   lams1[j,u] = softplus(sum_k Alpha[j,k]*Sval[k,u])  (u>=1; u==0 -> 0)
// ---------------------------------------------------------------------------
__global__ __launch_bounds__(256) void main_kernel(const float* __restrict__ obs,
                                                   const float* __restrict__ Beta,
                                                   const float* __restrict__ mu0,
                                                   const float* __restrict__ AT,
                                                   float* __restrict__ out) {
  __shared__ float Slds[TT][KK];  // 64 KB, [t][k]: writes conflict-free, reads broadcast
  const int tid = threadIdx.x;
  const int t0 = blockIdx.x * TT;

  // ---- scan phase: thread k computes Sval[k, t0..t0+TT) via W-step window ----
  {
    const int k = tid;
    const float beta = Beta[k];
    const float decay = __expf(-beta);
    const float* row = obs + (size_t)k * NN;
    float g = 0.f;  // approximates G[k, t0-WW] (tail < 1e-20)
    if (t0 > 0) {
      for (int s = t0 - WW; s < t0; ++s) g = decay * (g + row[s]);
    }
    Slds[0][k] = beta * g;  // u = t0  (t0==0 -> exactly 0)
#pragma unroll 4
    for (int i = 1; i < TT; ++i) {
      g = decay * (g + row[t0 + i - 1]);
      Slds[i][k] = beta * g;
    }
  }
  __syncthreads();

  // ---- GEMM: acc[jj][ii] = sum_k AT[k][j0+jj] * Slds[tl0+ii][k] ----
  const int jgrp = tid & 31;   // 32 groups x 8 j = 256 j
  const int tgrp = tid >> 5;   // 8 groups x 8 t = 64 t
  const int j0 = jgrp * 8;
  const int tl0 = tgrp * 8;

  float acc[8][8];
#pragma unroll
  for (int a = 0; a < 8; ++a)
#pragma unroll
    for (int b = 0; b < 8; ++b) acc[a][b] = 0.f;

  for (int k4 = 0; k4 < KK; k4 += 4) {
    float4 sv[8];
#pragma unroll
    for (int ii = 0; ii < 8; ++ii)
      sv[ii] = *(const float4*)&Slds[tl0 + ii][k4];
    float4 av[8];
#pragma unroll
    for (int kk = 0; kk < 4; ++kk) {
      const float* arow = AT + (size_t)(k4 + kk) * KK + j0;
      av[2 * kk]     = *(const float4*)(arow);
      av[2 * kk + 1] = *(const float4*)(arow + 4);
    }
#pragma unroll
    for (int kk = 0; kk < 4; ++kk) {
#pragma unroll
      for (int ii = 0; ii < 8; ++ii) {
        const float s = ((const float*)&sv[ii])[kk];
        const float* a8 = (const float*)&av[2 * kk];
#pragma unroll
        for (int jj = 0; jj < 8; ++jj)
          acc[jj][ii] += a8[jj] * s;
      }
    }
  }

  // ---- epilogue: softplus, lams1 store, loglik partial ----
  float partial = 0.f;
  float* lams1 = out + 1 + (size_t)KK * NN;
#pragma unroll
  for (int jj = 0; jj < 8; ++jj) {
    const int j = j0 + jj;
    const float m = mu0[j];
    const float* orow = obs + (size_t)j * NN + t0 + tl0;
    float* lrow = lams1 + (size_t)j * NN + t0 + tl0;
#pragma unroll
    for (int ii = 0; ii < 8; ++ii) {
      const float v = acc[jj][ii];                 // v >= 0 always
      float lam = v + __logf(1.f + __expf(-v));    // stable softplus
      if (t0 + tl0 + ii == 0) lam = 0.f;           // lams1[:,0] = 0 by definition
      lrow[ii] = lam;
      const float o = orow[ii];
      partial += o * __logf(m + lam + 1e-5f) - m - lam;
    }
  }

  // wave-level reduce, one atomic per wave (4096 atomics total)
#pragma unroll
  for (int off = 32; off > 0; off >>= 1)
    partial += __shfl_down(partial, off, 64);
  if ((tid & 63) == 0) atomicAdd(out, partial);
}

// ---------------------------------------------------------------------------
extern "C" void kernel_launch(void* const* d_in, const int* in_sizes, int n_in,
                              void* d_out, int out_size, void* d_ws, size_t ws_size,
                              hipStream_t stream) {
  const float* obs   = (const float*)d_in[0];
  const float* Beta  = (const float*)d_in[1];
  const float* Alpha = (const float*)d_in[2];
  float* out = (float*)d_out;

  float* mu0 = (float*)d_ws;        // 256 floats
  float* AT  = mu0 + 256;           // 65536 floats (Alpha transposed)

  hipLaunchKernelGGL(mu0_kernel, dim3(KK), dim3(256), 0, stream, obs, mu0, out);
  hipLaunchKernelGGL(prep_kernel, dim3(KK), dim3(256), 0, stream, Alpha, AT);
  hipLaunchKernelGGL(lams0_kernel, dim3((KK * NN) / 1024), dim3(256), 0, stream,
                     mu0, out + 1);
  hipLaunchKernelGGL(main_kernel, dim3(NN / TT), dim3(256), 0, stream,
                     obs, Beta, mu0, AT, out);
}

// Round 2
// 276.811 us; speedup vs baseline: 1.7259x; 1.7259x over previous
//
#include <hip/hip_runtime.h>
#include <math.h>

#define KK 256
#define NN 65536
#define TT 64    // time-tile columns per block
#define WW 48    // scan lookback window; decay<=e^-1 -> tail error ~1e-21
#define TPAD 264 // 256 + 8 bf16 pad: breaks 512B-stride bank aliasing, keeps 16B align

typedef __bf16 bf16x8 __attribute__((ext_vector_type(8)));
typedef float f32x4 __attribute__((ext_vector_type(4)));

// ---------------------------------------------------------------------------
// Kernel 1: partial row sums of obs. Block b: row r=b>>3, eighth e=b&7.
//   8192 floats per block = 2048 float4 = 256 threads x 8 float4.
// ---------------------------------------------------------------------------
__global__ __launch_bounds__(256) void rowsum_kernel(const float* __restrict__ obs,
                                                     float* __restrict__ partial) {
  const int b = blockIdx.x;
  const int r = b >> 3, e = b & 7;
  const int tid = threadIdx.x;
  const float4* p = (const float4*)(obs + (size_t)r * NN + e * 8192) + tid;
  float s = 0.f;
#pragma unroll
  for (int i = 0; i < 8; ++i) {
    float4 v = p[i * 256];
    s += (v.x + v.y) + (v.z + v.w);
  }
  __shared__ float red[256];
  red[tid] = s;
  __syncthreads();
  for (int off = 128; off > 0; off >>= 1) {
    if (tid < off) red[tid] += red[tid + off];
    __syncthreads();
  }
  if (tid == 0) partial[b] = red[0];
}

// ---------------------------------------------------------------------------
// Kernel 2: finalize mu0, convert Alpha -> bf16, zero loglik accumulator.
//   Block j handles Alpha row j (256 elems).
// ---------------------------------------------------------------------------
__global__ __launch_bounds__(256) void prep_kernel(const float* __restrict__ Alpha,
                                                   const float* __restrict__ partial,
                                                   float* __restrict__ mu0,
                                                   __bf16* __restrict__ AlphaB,
                                                   float* __restrict__ out) {
  const int j = blockIdx.x;
  const int tid = threadIdx.x;
  AlphaB[(size_t)j * KK + tid] = (__bf16)Alpha[(size_t)j * KK + tid];
  if (tid == 0) {
    float s = 0.f;
#pragma unroll
    for (int i = 0; i < 8; ++i) s += partial[j * 8 + i];
    mu0[j] = s * (1.0f / NN) * 0.1f + 0.01f;
    if (j == 0) out[0] = 0.f;  // zero loglik accumulator (d_out poisoned)
  }
}

// ---------------------------------------------------------------------------
// Kernel 3: fused windowed-scan + bf16-MFMA GEMM + softplus + lams0/lams1 +
//           loglik partial. Block b covers t in [b*TT, b*TT+TT).
//   MFMA 16x16x32 bf16; A = Alpha[j][k] (row-major bf16), B = S[k][t] served
//   from LDS stored [t][k] so B-frag k-octets are contiguous 16B.
// ---------------------------------------------------------------------------
__global__ __launch_bounds__(256, 2) void main_kernel(const float* __restrict__ obs,
                                                      const float* __restrict__ Beta,
                                                      const float* __restrict__ mu0,
                                                      const __bf16* __restrict__ AlphaB,
                                                      float* __restrict__ out) {
  __shared__ __bf16 Slds[TT][TPAD];  // 33.8 KB
  const int tid = threadIdx.x;
  const int t0 = blockIdx.x * TT;

  // ---- scan phase: thread k computes S[k, t0..t0+63] via WW-step window ----
  {
    const int k = tid;
    const float beta = Beta[k];
    const float decay = expf(-beta);
    const float* row = obs + (size_t)k * NN;
    float g = 0.f;  // ~ G[k, t0-WW]; tail < e^-48
    if (t0 > 0) {
      const float4* p = (const float4*)(row + t0 - WW);
#pragma unroll
      for (int i = 0; i < WW / 4; ++i) {
        float4 v = p[i];
        g = decay * (g + v.x);
        g = decay * (g + v.y);
        g = decay * (g + v.z);
        g = decay * (g + v.w);
      }
    }
    Slds[0][k] = (__bf16)(beta * g);
    const float4* q = (const float4*)(row + t0);
#pragma unroll
    for (int i = 0; i < 15; ++i) {
      float4 v = q[i];
      g = decay * (g + v.x); Slds[4 * i + 1][k] = (__bf16)(beta * g);
      g = decay * (g + v.y); Slds[4 * i + 2][k] = (__bf16)(beta * g);
      g = decay * (g + v.z); Slds[4 * i + 3][k] = (__bf16)(beta * g);
      g = decay * (g + v.w); Slds[4 * i + 4][k] = (__bf16)(beta * g);
    }
    {  // tail: obs t0+60..62 -> S[61..63]
      float4 v = q[15];
      g = decay * (g + v.x); Slds[61][k] = (__bf16)(beta * g);
      g = decay * (g + v.y); Slds[62][k] = (__bf16)(beta * g);
      g = decay * (g + v.z); Slds[63][k] = (__bf16)(beta * g);
    }
  }
  __syncthreads();

  // ---- MFMA GEMM: wave w covers j in [64w, 64w+64), all 64 t ----
  const int wave = tid >> 6;
  const int lane = tid & 63;
  const int lquad = lane >> 4;  // 0..3 -> k-octet within K=32 step / j-sub in C
  const int l16 = lane & 15;

  f32x4 acc[4][4];  // [jsub][tsub]
#pragma unroll
  for (int a = 0; a < 4; ++a)
#pragma unroll
    for (int b = 0; b < 4; ++b) acc[a][b] = (f32x4){0.f, 0.f, 0.f, 0.f};

  const __bf16* Abase = AlphaB + (size_t)(wave * 64 + l16) * KK + lquad * 8;
  for (int k0 = 0; k0 < KK; k0 += 32) {
    bf16x8 afrag[4], bfrag[4];
#pragma unroll
    for (int js = 0; js < 4; ++js)
      afrag[js] = *(const bf16x8*)(Abase + (size_t)js * 16 * KK + k0);
#pragma unroll
    for (int ts = 0; ts < 4; ++ts)
      bfrag[ts] = *(const bf16x8*)&Slds[ts * 16 + l16][k0 + lquad * 8];
#pragma unroll
    for (int js = 0; js < 4; ++js)
#pragma unroll
      for (int ts = 0; ts < 4; ++ts)
        acc[js][ts] = __builtin_amdgcn_mfma_f32_16x16x32_bf16(
            afrag[js], bfrag[ts], acc[js][ts], 0, 0, 0);
  }

  // ---- epilogue: softplus, lams0/lams1 stores, loglik partial ----
  float partial = 0.f;
  float* lams0 = out + 1;
  float* lams1 = out + 1 + (size_t)KK * NN;
#pragma unroll
  for (int js = 0; js < 4; ++js) {
#pragma unroll
    for (int r = 0; r < 4; ++r) {
      const int j = wave * 64 + js * 16 + lquad * 4 + r;  // D row mapping
      const float m = mu0[j];
      const size_t rowoff = (size_t)j * NN + t0 + l16;
#pragma unroll
      for (int ts = 0; ts < 4; ++ts) {
        float v = acc[js][ts][r];                    // v >= 0 always
        float lam = v + __logf(1.f + __expf(-v));    // stable softplus
        if (t0 + ts * 16 + l16 == 0) lam = 0.f;      // lams1[:,0] = 0
        lams1[rowoff + ts * 16] = lam;
        lams0[rowoff + ts * 16] = m;
        const float o = obs[rowoff + ts * 16];
        partial += o * __logf(m + lam + 1e-5f) - m - lam;
      }
    }
  }

  // wave reduce, one atomic per wave
#pragma unroll
  for (int off = 32; off > 0; off >>= 1)
    partial += __shfl_down(partial, off, 64);
  if (lane == 0) atomicAdd(out, partial);
}

// ---------------------------------------------------------------------------
extern "C" void kernel_launch(void* const* d_in, const int* in_sizes, int n_in,
                              void* d_out, int out_size, void* d_ws, size_t ws_size,
                              hipStream_t stream) {
  const float* obs   = (const float*)d_in[0];
  const float* Beta  = (const float*)d_in[1];
  const float* Alpha = (const float*)d_in[2];
  float* out = (float*)d_out;

  float* partial = (float*)d_ws;            // 2048 floats
  float* mu0 = partial + 2048;              // 256 floats
  __bf16* AlphaB = (__bf16*)(mu0 + 256);    // 65536 bf16

  hipLaunchKernelGGL(rowsum_kernel, dim3(KK * 8), dim3(256), 0, stream, obs, partial);
  hipLaunchKernelGGL(prep_kernel, dim3(KK), dim3(256), 0, stream, Alpha, partial,
                     mu0, AlphaB, out);
  hipLaunchKernelGGL(main_kernel, dim3(NN / TT), dim3(256), 0, stream,
                     obs, Beta, mu0, AlphaB, out);
}